// Round 1
// baseline (274.637 us; speedup 1.0000x reference)
//
#include <hip/hip_runtime.h>
#include <hip/hip_bf16.h>

// GAT layer: B=8, N=2048, Fin=Fout=256
// h (f32), adj (i32 0/1), W (f32 256x256), a (f32 512x1) -> out f32 (8,2048,256)

typedef __bf16 bf16x8 __attribute__((ext_vector_type(8)));
typedef float f32x4 __attribute__((ext_vector_type(4)));
typedef unsigned short u16x8 __attribute__((ext_vector_type(8)));

__device__ __forceinline__ unsigned short f2bf(float f) {
    unsigned int u = __float_as_uint(f);
    u += 0x7FFFu + ((u >> 16) & 1u);   // round-to-nearest-even
    return (unsigned short)(u >> 16);
}

__device__ __forceinline__ void gld_lds16(const void* g, void* l) {
    __builtin_amdgcn_global_load_lds(
        (const __attribute__((address_space(1))) unsigned int*)g,
        (__attribute__((address_space(3))) unsigned int*)l, 16, 0, 0);
}

// ---------------- K0: WT = W^T (bf16), wa1/wa2 = W@a1, W@a2 (f32) ----------
__global__ void k_prep(const float* __restrict__ W, const float* __restrict__ a,
                       unsigned short* __restrict__ WT,
                       float* __restrict__ wa1, float* __restrict__ wa2) {
    int t = threadIdx.x;
    int bid = blockIdx.x;
    if (bid < 256) {
        int o = bid;
        WT[o * 256 + t] = f2bf(W[t * 256 + o]);   // coalesced write per column
    } else {
        float a1v, a2v, acc1 = 0.f, acc2 = 0.f;
        for (int o = 0; o < 256; o++) {
            float w = W[t * 256 + o];
            a1v = a[o]; a2v = a[256 + o];
            acc1 += w * a1v;
            acc2 += w * a2v;
        }
        wa1[t] = acc1; wa2[t] = acc2;
    }
}

// ---------------- K1: s1[r]=h[r]·wa1, s2[r]=h[r]·wa2  (full f32) -----------
__global__ void k_scores(const float* __restrict__ h, const float* __restrict__ wa1,
                         const float* __restrict__ wa2,
                         float* __restrict__ s1, float* __restrict__ s2) {
    __shared__ float w1[256], w2[256];
    int t = threadIdx.x;
    w1[t] = wa1[t]; w2[t] = wa2[t];
    __syncthreads();
    int r = blockIdx.x * 256 + t;
    const float* hr = h + (size_t)r * 256;
    float acc1 = 0.f, acc2 = 0.f;
#pragma unroll 4
    for (int i = 0; i < 256; i += 4) {
        float4 v = *(const float4*)(hr + i);
        acc1 += v.x * w1[i] + v.y * w1[i + 1] + v.z * w1[i + 2] + v.w * w1[i + 3];
        acc2 += v.x * w2[i] + v.y * w2[i + 1] + v.z * w2[i + 2] + v.w * w2[i + 3];
    }
    s1[r] = acc1; s2[r] = acc2;
}

// ---------------- K2: whT[o][r] = bf16( (h@W)[r][o] ) ----------------------
// block = 64o x 64r tile, K=256 fully staged. acc[o][r]: A=W^T, B=h (row-major K-consecutive).
__global__ __launch_bounds__(256, 2)
void k_whT(const float* __restrict__ h, const unsigned short* __restrict__ WT,
           unsigned short* __restrict__ whT) {
    __shared__ __align__(16) unsigned char smem[65536]; // [0,32K): WT tile, [32K,64K): h tile / epilogue
    int tid = threadIdx.x, w = tid >> 6, l = tid & 63;
    int bid = blockIdx.x, ot = bid & 3, rt = bid >> 2;
    unsigned short* h_lds = (unsigned short*)(smem + 32768);

    // stage W^T tile [64o][256i] bf16 via global_load_lds, source pre-swizzled
    {
        const unsigned char* WTb = (const unsigned char*)WT + (size_t)ot * 32768;
#pragma unroll
        for (int j = 0; j < 8; j++) {
            int chunk = w * 8 + j;
            int o = chunk * 2 + (l >> 5);
            int kb = (l & 31) * 16;
            gld_lds16(WTb + o * 512 + (kb ^ ((o & 7) << 4)), smem + chunk * 1024);
        }
    }
    // stage h tile [64r][256i] f32->bf16, XOR-swizzled writes
    {
        int rl = tid >> 2, cs = tid & 3;
        const float* hp = h + ((size_t)(rt * 64 + rl)) * 256 + cs * 64;
        int swz = (rl & 7) << 4;
        unsigned char* dst = (unsigned char*)(h_lds + rl * 256);
#pragma unroll
        for (int q = 0; q < 8; q++) {
            float4 v0 = *(const float4*)(hp + q * 8);
            float4 v1 = *(const float4*)(hp + q * 8 + 4);
            u16x8 pk;
            pk[0] = f2bf(v0.x); pk[1] = f2bf(v0.y); pk[2] = f2bf(v0.z); pk[3] = f2bf(v0.w);
            pk[4] = f2bf(v1.x); pk[5] = f2bf(v1.y); pk[6] = f2bf(v1.z); pk[7] = f2bf(v1.w);
            *(u16x8*)(dst + ((cs * 128 + q * 16) ^ swz)) = pk;
        }
    }
    __syncthreads();

    int l15 = l & 15, g = l >> 4;
    int oh = (w & 1) * 32, rh = (w >> 1) * 32;
    int swzr = (l15 & 7) << 4;
    f32x4 acc[2][2] = {};
#pragma unroll
    for (int kc = 0; kc < 8; kc++) {
        int kbyte = kc * 64 + 16 * g;
        bf16x8 A[2], Bv[2];
#pragma unroll
        for (int oi = 0; oi < 2; oi++)
            A[oi] = *(const bf16x8*)(smem + (oh + oi * 16 + l15) * 512 + (kbyte ^ swzr));
#pragma unroll
        for (int rj = 0; rj < 2; rj++)
            Bv[rj] = *(const bf16x8*)((unsigned char*)h_lds + (rh + rj * 16 + l15) * 512 + (kbyte ^ swzr));
#pragma unroll
        for (int oi = 0; oi < 2; oi++)
#pragma unroll
            for (int rj = 0; rj < 2; rj++)
                acc[oi][rj] = __builtin_amdgcn_mfma_f32_16x16x32_bf16(A[oi], Bv[rj], acc[oi][rj], 0, 0, 0);
    }
    __syncthreads();
    // epilogue: transpose-store via LDS, [64o][72r] bf16 (aliases h tile)
    unsigned short* LT = h_lds;
#pragma unroll
    for (int oi = 0; oi < 2; oi++)
#pragma unroll
        for (int rj = 0; rj < 2; rj++)
#pragma unroll
            for (int jj = 0; jj < 4; jj++) {
                int o = oh + oi * 16 + g * 4 + jj;
                int r = rh + rj * 16 + l15;
                LT[o * 72 + r] = f2bf(acc[oi][rj][jj]);
            }
    __syncthreads();
    {
        int o = tid >> 2, seg = tid & 3;
        u16x8 v0 = *(const u16x8*)(LT + o * 72 + seg * 16);
        u16x8 v1 = *(const u16x8*)(LT + o * 72 + seg * 16 + 8);
        unsigned short* dst = whT + (size_t)(ot * 64 + o) * 16384 + rt * 64 + seg * 16;
        *(u16x8*)dst = v0;
        *(u16x8*)(dst + 8) = v1;
    }
}

// ---------------- K3: fused mask/exp/softmax/PV ----------------------------
// block = (batch b, 32 m-rows); acc[o][m] = sum_n p[m][n]*wh[n][o]; rowsum via ones-A MFMA.
// LDS: [0,32K) WHT tile [256o][64k] bf16 (linear, src-swizzled); P [32][72] bf16; s2; s1; rowsum.
__global__ __launch_bounds__(256, 2)
void k_attn(const int* __restrict__ adj, const unsigned short* __restrict__ whT,
            const float* __restrict__ s1, const float* __restrict__ s2,
            float* __restrict__ out) {
    __shared__ __align__(16) unsigned char smem[45824];
    int tid = threadIdx.x, w = tid >> 6, l = tid & 63;
    int b = blockIdx.x & 7, mt = blockIdx.x >> 3;   // b = XCD affinity: whT[b] stays L2-resident
    int m0 = mt * 32;
    unsigned short* P = (unsigned short*)(smem + 32768);
    float* S2 = (float*)(smem + 37376);
    float* S1 = (float*)(smem + 45568);
    float* RS = (float*)(smem + 45696);

    if (tid < 32) S1[tid] = s1[b * 2048 + m0 + tid];
    {
        const float* sp = s2 + b * 2048 + tid * 8;
        *(float4*)(S2 + tid * 8) = *(const float4*)sp;
        *(float4*)(S2 + tid * 8 + 4) = *(const float4*)(sp + 4);
    }
    __syncthreads();

    f32x4 acc[4][2] = {};
    f32x4 rs[2] = {};
    u16x8 onesu;
#pragma unroll
    for (int i = 0; i < 8; i++) onesu[i] = 0x3F80;  // bf16 1.0
    bf16x8 ones = *(bf16x8*)&onesu;

    int tm = tid >> 3, ts = tid & 7;
    const int* adjRow = adj + ((size_t)b * 2048 + m0 + tm) * 2048;
    float s1v = S1[tm];
    int l15 = l & 15, g = l >> 4;
    int swz = (l15 & 7) << 4;
    const unsigned char* src0 = (const unsigned char*)whT + (size_t)(b * 2048) * 2;

    for (int nt = 0; nt < 32; nt++) {
        int n0 = nt * 64;
        // stage whT tile [256o][64k] via global_load_lds (source XOR-pre-swizzled)
#pragma unroll
        for (int j = 0; j < 8; j++) {
            int chunk = w * 8 + j;
            int o = chunk * 8 + (l >> 3);
            int kb = (l & 7) * 16;
            gld_lds16(src0 + (size_t)o * 32768 + n0 * 2 + (kb ^ ((o & 7) << 4)),
                      smem + chunk * 1024);
        }
        // compute P[m][k] = adj ? exp(LeakyReLU(s1+s2)) : 0   (bf16)
        {
            int4 A0 = *(const int4*)(adjRow + n0 + ts * 8);
            int4 A1 = *(const int4*)(adjRow + n0 + ts * 8 + 4);
            const float* s2p = S2 + n0 + ts * 8;
            int av[8] = {A0.x, A0.y, A0.z, A0.w, A1.x, A1.y, A1.z, A1.w};
            u16x8 pk;
#pragma unroll
            for (int e = 0; e < 8; e++) {
                float x = s1v + s2p[e];
                x = x > 0.f ? x : 0.2f * x;
                float p = av[e] > 0 ? __expf(x) : 0.f;
                pk[e] = f2bf(p);
            }
            *(u16x8*)((unsigned char*)P + tm * 144 + ts * 16) = pk;
        }
        __syncthreads();
        // MFMA: wave w owns o in [w*64, w*64+64)
#pragma unroll
        for (int kc = 0; kc < 2; kc++) {
            int kbyte = kc * 64 + 16 * g;
            bf16x8 Bv[2];
#pragma unroll
            for (int mj = 0; mj < 2; mj++)
                Bv[mj] = *(const bf16x8*)((unsigned char*)P + (mj * 16 + l15) * 144 + kbyte);
#pragma unroll
            for (int oi = 0; oi < 4; oi++) {
                bf16x8 Av = *(const bf16x8*)(smem + (w * 64 + oi * 16 + l15) * 128 + (kbyte ^ swz));
#pragma unroll
                for (int mj = 0; mj < 2; mj++)
                    acc[oi][mj] = __builtin_amdgcn_mfma_f32_16x16x32_bf16(Av, Bv[mj], acc[oi][mj], 0, 0, 0);
            }
            if (w == 0) {
#pragma unroll
                for (int mj = 0; mj < 2; mj++)
                    rs[mj] = __builtin_amdgcn_mfma_f32_16x16x32_bf16(ones, Bv[mj], rs[mj], 0, 0, 0);
            }
        }
        __syncthreads();
    }
    if (w == 0 && l < 16) { RS[l] = rs[0][0]; RS[16 + l] = rs[1][0]; }
    __syncthreads();
    // epilogue: normalize + transpose via LDS, coalesced f32 stores
    float inv[2];
#pragma unroll
    for (int mj = 0; mj < 2; mj++) {
        float r_ = RS[mj * 16 + l15];
        inv[mj] = r_ > 0.f ? 1.0f / r_ : 0.f;
    }
    float* EP = (float*)(smem + w * 8704);   // [32m][68o] per wave
#pragma unroll
    for (int oi = 0; oi < 4; oi++)
#pragma unroll
        for (int mj = 0; mj < 2; mj++)
#pragma unroll
            for (int jj = 0; jj < 4; jj++)
                EP[(mj * 16 + l15) * 68 + oi * 16 + g * 4 + jj] = acc[oi][mj][jj] * inv[mj];
    __syncthreads();
    {
        int lm = l >> 3, os = l & 7;
#pragma unroll
        for (int mq = 0; mq < 4; mq++) {
            int m = mq * 8 + lm;
            f32x4 v0 = *(const f32x4*)(EP + m * 68 + os * 8);
            f32x4 v1 = *(const f32x4*)(EP + m * 68 + os * 8 + 4);
            float* dst = out + ((size_t)b * 2048 + m0 + m) * 256 + w * 64 + os * 8;
            *(f32x4*)dst = v0;
            *(f32x4*)(dst + 4) = v1;
        }
    }
}

extern "C" void kernel_launch(void* const* d_in, const int* in_sizes, int n_in,
                              void* d_out, int out_size, void* d_ws, size_t ws_size,
                              hipStream_t stream) {
    const float* h = (const float*)d_in[0];
    const int* adj = (const int*)d_in[1];
    const float* W = (const float*)d_in[2];
    const float* a = (const float*)d_in[3];
    float* out = (float*)d_out;

    unsigned char* ws = (unsigned char*)d_ws;
    unsigned short* whT = (unsigned short*)ws;              // 256*16384*2 = 8388608
    unsigned short* WT  = (unsigned short*)(ws + 8388608);  // 131072
    float* wa1 = (float*)(ws + 8519680);                    // 1024
    float* wa2 = (float*)(ws + 8520704);                    // 1024
    float* s1  = (float*)(ws + 8521728);                    // 65536
    float* s2  = (float*)(ws + 8587264);                    // 65536  (total ~8.65 MB)

    k_prep  <<<257,  256, 0, stream>>>(W, a, WT, wa1, wa2);
    k_scores<<<64,   256, 0, stream>>>(h, wa1, wa2, s1, s2);
    k_whT   <<<1024, 256, 0, stream>>>(h, WT, whT);
    k_attn  <<<512,  256, 0, stream>>>(adj, whT, s1, s2, out);
}